// Round 11
// baseline (227.142 us; speedup 1.0000x reference)
//
#include <hip/hip_runtime.h>
#include <hip/hip_bf16.h>
#include <math.h>

#define DM   1024
#define HD   1024
#define NH   16
#define DK   64
#define SEQ  2048
#define BATCH 2

#define LOG2E 1.4426950408889634f
#define FIXB 32.0f   // fixed softmax base (log2 domain); |logits| << 32+120

typedef __attribute__((ext_vector_type(8))) short bf16x8;
typedef __attribute__((ext_vector_type(4))) float f32x4;

static __device__ __forceinline__ short f2b(float f) {
  union { float f; unsigned u; } v; v.f = f;
  unsigned r = (v.u + 0x7fffu + ((v.u >> 16) & 1u)) >> 16;
  return (short)r;
}

// HW packed f32->bf16 (RNE), lo = src0, hi = src1  [T12, gfx950]
static __device__ __forceinline__ int cvt_pk(float lo, float hi) {
  int r;
  asm("v_cvt_pk_bf16_f32 %0, %1, %2" : "=v"(r) : "v"(lo), "v"(hi));
  return r;
}

static __device__ __forceinline__ void gload_lds16(const void* g, void* l) {
  __builtin_amdgcn_global_load_lds(
      (const __attribute__((address_space(1))) void*)g,
      (__attribute__((address_space(3))) void*)l, 16, 0, 0);
}

// ---------------- prep kernels ----------------

__global__ __launch_bounds__(256) void k_cvt_h(const float* __restrict__ in,
                                               short* __restrict__ out) {
  int i = (blockIdx.x * 256 + threadIdx.x) * 8;
  float4 a = *reinterpret_cast<const float4*>(in + i);
  float4 b = *reinterpret_cast<const float4*>(in + i + 4);
  bf16x8 o;
  o[0] = f2b(a.x); o[1] = f2b(a.y); o[2] = f2b(a.z); o[3] = f2b(a.w);
  o[4] = f2b(b.x); o[5] = f2b(b.y); o[6] = f2b(b.z); o[7] = f2b(b.w);
  *reinterpret_cast<bf16x8*>(out + i) = o;
}

// transpose + convert 1024x1024 fp32 [K][N] -> bf16 [N][K]; z selects matrix.
// Wq (z==0) is pre-scaled by log2e so attention logits are in log2 domain.
__global__ __launch_bounds__(256) void k_wtrans(const float* __restrict__ Wq,
                                                const float* __restrict__ Wk,
                                                const float* __restrict__ Wv,
                                                const float* __restrict__ Wo,
                                                short* __restrict__ Wts) {
  const float* src = (blockIdx.z == 0) ? Wq : (blockIdx.z == 1) ? Wk
                   : (blockIdx.z == 2) ? Wv : Wo;
  const float scl = (blockIdx.z == 0) ? LOG2E : 1.0f;
  short* dst = Wts + (size_t)blockIdx.z * DM * HD;
  __shared__ float t[32][33];
  int tx = threadIdx.x & 31, ty = threadIdx.x >> 5;  // ty 0..7
  int k0 = blockIdx.y * 32, n0 = blockIdx.x * 32;
#pragma unroll
  for (int i = 0; i < 4; ++i)
    t[ty + i * 8][tx] = src[(size_t)(k0 + ty + i * 8) * 1024 + n0 + tx];
  __syncthreads();
#pragma unroll
  for (int i = 0; i < 4; ++i)
    dst[(size_t)(n0 + ty + i * 8) * 1024 + k0 + tx] = f2b(t[tx][ty + i * 8] * scl);
}

// bias table (scaled by log2e): btab[h][pos], pos = delta + 2047, delta = kv-q
__global__ __launch_bounds__(256) void k_bias(const float* __restrict__ rel_bias,
                                              float* __restrict__ btab) {
  int idx = blockIdx.x * 256 + threadIdx.x;  // 65536
  int h = idx >> 12, pos = idx & 4095;
  int delta = pos - 2047;
  int rb = (delta > 0) ? 16 : 0;
  int ar = (delta < 0) ? -delta : delta;
  int bb;
  if (ar < 8) bb = ar;
  else {
    bb = 8 + (int)(logf((float)ar * 0.125f) * (8.0f / 2.7725887222397811f));
    if (bb > 15) bb = 15;
  }
  btab[idx] = rel_bias[(rb + bb) * NH + h] * LOG2E;
}

// V [4096][1024] bf16 -> Vt[bh][dk=64][seq=2048] with the PV k-permutation
// baked in: within each 32-kv chunk, 4-kv blocks stored in order
// [0,4,1,5,2,6,3,7] so lane lg's PV A-frag (kv lg*4+r and 16+lg*4+r) is one
// contiguous b128 at byte offset lg*16 / 64+lg*16.
__global__ __launch_bounds__(256) void k_vtrans(const short* __restrict__ Vb,
                                                short* __restrict__ Vt) {
  int bh = blockIdx.y, b = bh >> 4, h = bh & 15;
  int st = blockIdx.x * 64;
  __shared__ short t[64][72];
  int tx = threadIdx.x & 15, ty = threadIdx.x >> 4;
#pragma unroll
  for (int i = 0; i < 4; ++i) {
    int row = ty + i * 16;
    *reinterpret_cast<short4*>(&t[row][tx * 4]) =
        *reinterpret_cast<const short4*>(
            &Vb[(size_t)(b * SEQ + st + row) * HD + h * 64 + tx * 4]);
  }
  __syncthreads();
  const int chunk = tx >> 3, bb = tx & 7;
  const int p = ((bb & 3) << 1) | (bb >> 2);  // stored block position
  const int kvpos = st + chunk * 32 + p * 4;
#pragma unroll
  for (int i = 0; i < 4; ++i) {
    int dk = ty + i * 16;
    short4 v = make_short4(t[tx * 4 + 0][dk], t[tx * 4 + 1][dk],
                           t[tx * 4 + 2][dk], t[tx * 4 + 3][dk]);
    *reinterpret_cast<short4*>(
        &Vt[(size_t)bh * DK * SEQ + (size_t)dk * SEQ + kvpos]) = v;
  }
}

// ---------------- GEMM: C[M][1024] = A[M][1024]bf16 * Bt[1024][1024]bf16^T ----
// 128x128 tile, 4 waves, K-step 32 — triple-buffered with COUNTED vmcnt (T4)
// across raw s_barrier (no __syncthreads: it would drain vmcnt to 0).
static __device__ __forceinline__ void gemm_stage(const short* Ap1, const short* Ap2,
                                                  const short* Bp1, const short* Bp2,
                                                  int k0, char* AsB, char* BsB, int w) {
  gload_lds16(Ap1 + k0, AsB + w * 1024);
  gload_lds16(Ap2 + k0, AsB + 4096 + w * 1024);
  gload_lds16(Bp1 + k0, BsB + w * 1024);
  gload_lds16(Bp2 + k0, BsB + 4096 + w * 1024);
}

template <int OUTF32>
__global__ __launch_bounds__(256) void k_gemm_bt(const short* __restrict__ A,
                                                 const short* __restrict__ Bt,
                                                 void* __restrict__ Cv,
                                                 size_t btz, size_t cz) {
  __shared__ __align__(16) short As[3][128 * 32];
  __shared__ __align__(16) short Bs[3][128 * 32];
  const int tid = threadIdx.x, w = tid >> 6, lane = tid & 63;
  const int wr = w >> 1, wc = w & 1, lg = lane >> 4, l15 = lane & 15;
  const int rowBase = blockIdx.y * 128, colBase = blockIdx.x * 128;
  const short* B = Bt + (size_t)blockIdx.z * btz;

  f32x4 acc[4][4];
#pragma unroll
  for (int m = 0; m < 4; ++m)
#pragma unroll
    for (int n = 0; n < 4; ++n) acc[m][n] = (f32x4){0.f, 0.f, 0.f, 0.f};

  const int c1 = w * 64 + lane, c2 = c1 + 256;
  const short* Ap1 = A + (size_t)(rowBase + (c1 >> 2)) * 1024 + (c1 & 3) * 8;
  const short* Ap2 = A + (size_t)(rowBase + (c2 >> 2)) * 1024 + (c2 & 3) * 8;
  const short* Bp1 = B + (size_t)(colBase + (c1 >> 2)) * 1024 + (c1 & 3) * 8;
  const short* Bp2 = B + (size_t)(colBase + (c2 >> 2)) * 1024 + (c2 & 3) * 8;

  // prologue: stage K-tiles 0 and 1; wait only tile 0 (4 oldest of 8)
  gemm_stage(Ap1, Ap2, Bp1, Bp2, 0, (char*)As[0], (char*)Bs[0], w);
  gemm_stage(Ap1, Ap2, Bp1, Bp2, 32, (char*)As[1], (char*)Bs[1], w);
  asm volatile("s_waitcnt vmcnt(4)" ::: "memory");
  __builtin_amdgcn_s_barrier();
  __builtin_amdgcn_sched_barrier(0);
  int cur = 0;

  for (int k0 = 0; k0 < 1024; k0 += 32) {
    int nx2 = cur + 2; if (nx2 >= 3) nx2 -= 3;
    // issue tile t+2 (2 ahead) — stays in flight across this iter's barrier
    if (k0 < 960)
      gemm_stage(Ap1, Ap2, Bp1, Bp2, k0 + 64, (char*)As[nx2], (char*)Bs[nx2], w);
    bf16x8 af[4], bfr[4];
#pragma unroll
    for (int m = 0; m < 4; ++m)
      af[m] = *reinterpret_cast<const bf16x8*>(
          &As[cur][(wr * 64 + m * 16 + l15) * 32 + lg * 8]);
#pragma unroll
    for (int n = 0; n < 4; ++n)
      bfr[n] = *reinterpret_cast<const bf16x8*>(
          &Bs[cur][(wc * 64 + n * 16 + l15) * 32 + lg * 8]);
#pragma unroll
    for (int m = 0; m < 4; ++m)
#pragma unroll
      for (int n = 0; n < 4; ++n)
        acc[m][n] =
            __builtin_amdgcn_mfma_f32_16x16x32_bf16(af[m], bfr[n], acc[m][n], 0, 0, 0);
    // counted wait: tile t+1 (4 oldest) done; tile t+2 still in flight
    if (k0 < 960) {
      asm volatile("s_waitcnt vmcnt(4)" ::: "memory");
    } else {
      asm volatile("s_waitcnt vmcnt(0)" ::: "memory");
    }
    __builtin_amdgcn_s_barrier();
    __builtin_amdgcn_sched_barrier(0);
    cur = cur + 1; if (cur >= 3) cur = 0;
  }

#pragma unroll
  for (int m = 0; m < 4; ++m)
#pragma unroll
    for (int n = 0; n < 4; ++n) {
      int col = colBase + wc * 64 + n * 16 + l15;
#pragma unroll
      for (int r = 0; r < 4; ++r) {
        int row = rowBase + wr * 64 + m * 16 + lg * 4 + r;
        if (OUTF32)
          ((float*)Cv)[(size_t)row * 1024 + col] = acc[m][n][r];
        else
          ((short*)Cv + (size_t)blockIdx.z * cz)[(size_t)row * 1024 + col] =
              f2b(acc[m][n][r]);
      }
    }
}

// ---------------- flash attention (fixed-base softmax, zero-shuffle PV) -----
// K/V tiles: LDS(row, cb) = G(row, cb ^ ((row&7)<<4)) — linear gload_lds dest,
// inverse-swizzled per-lane global source, swizzled ds_read (rule 21 / T2).
static __device__ __forceinline__ void stage_tile(const char* gbase, size_t grs,
                                                  char* lbase, int w, int lane) {
  const int r0 = w * 16 + (lane >> 3);
  const int cb = (lane & 7) * 16;
  const int sw = (r0 & 7) << 4;  // (r0+8)&7 == r0&7
  gload_lds16(gbase + (size_t)r0 * grs + (cb ^ sw), lbase + w * 2048);
  gload_lds16(gbase + (size_t)(r0 + 8) * grs + (cb ^ sw), lbase + w * 2048 + 1024);
}

// Fixed-base softmax: P = 2^(S - 32), l = sum P, out = (sum P*V)/l.
// Triple-buffered K/V staging with counted vmcnt across raw s_barrier (T4):
// per wave per tile = 4 loads (K:2, V:2); stage 2 tiles ahead; end-of-iter
// vmcnt(4) retires exactly tile t+1, leaves tile t+2 in flight.
__global__ __launch_bounds__(256, 3) void k_attn(const short* __restrict__ Qb,
                                                 const short* __restrict__ Kb,
                                                 const short* __restrict__ Vt,
                                                 const float* __restrict__ biasTab,
                                                 short* __restrict__ Ob) {
  const int j = blockIdx.x;
  const int orig = (j & 7) * 128 + (j >> 3);  // bijective XCD swizzle (1024%8==0)
  const int qt = orig & 31, bh = orig >> 5;
  const int b = bh >> 4, h = bh & 15;
  const int w = threadIdx.x >> 6, lane = threadIdx.x & 63;
  const int lg = lane >> 4, l15 = lane & 15;
  const int qbase = qt * 64 + w * 16;

  __shared__ __align__(16) char Ks[3][8192];
  __shared__ __align__(16) char Vs[3][8192];
  const int swz = (l15 & 7) << 4;

  const short* Qrow = Qb + (size_t)(b * SEQ + qbase + l15) * HD + h * 64 + lg * 8;
  bf16x8 q0 = *reinterpret_cast<const bf16x8*>(Qrow);
  bf16x8 q1 = *reinterpret_cast<const bf16x8*>(Qrow + 32);

  const char* Kg = (const char*)(Kb + (size_t)(b * SEQ) * HD + h * 64);
  const char* Vg = (const char*)(Vt + (size_t)bh * DK * SEQ);
  const float* btab = biasTab + h * 4096 + 2047;
  const float bias_hi = btab[1024];   // saturated delta >= +91
  const float bias_lo = btab[-1024];  // saturated delta <= -91

  f32x4 o[4];
#pragma unroll
  for (int c = 0; c < 4; ++c) o[c] = (f32x4){0.f, 0.f, 0.f, 0.f};
  float l_r = 0.f;

  const f32x4 z4 = (f32x4){0.f, 0.f, 0.f, 0.f};

  // prologue: stage tiles 0 and 1; wait only tile 0 (4 oldest of 8)
  stage_tile(Kg, 2048, Ks[0], w, lane);
  stage_tile(Vg, 4096, Vs[0], w, lane);
  stage_tile(Kg + (size_t)64 * 2048, 2048, Ks[1], w, lane);
  stage_tile(Vg + (size_t)64 * 2, 4096, Vs[1], w, lane);
  asm volatile("s_waitcnt vmcnt(4)" ::: "memory");
  __builtin_amdgcn_s_barrier();
  __builtin_amdgcn_sched_barrier(0);
  int cur = 0;

  for (int kt = 0; kt < 32; ++kt) {
    const int kvb = kt * 64;
    const int dkv = kvb - qbase;
    // ---- issue tile kt+2 staging (in flight across this iter's barrier)
    int nx2 = cur + 2; if (nx2 >= 3) nx2 -= 3;
    if (kt < 30) {
      stage_tile(Kg + (size_t)(kvb + 128) * 2048, 2048, Ks[nx2], w, lane);
      stage_tile(Vg + (size_t)(kvb + 128) * 2, 4096, Vs[nx2], w, lane);
    }
    // ---- S^T = K Q^T : col=q(l15), row=kv(c*16+lg*4+r); log2 domain
    const char* KsC = Ks[cur];
    f32x4 s[4];
    __builtin_amdgcn_s_setprio(1);
#pragma unroll
    for (int c = 0; c < 4; ++c) {
      const char* kr = KsC + (c * 16 + l15) * 128;
      bf16x8 kf0 = *reinterpret_cast<const bf16x8*>(kr + ((lg * 16) ^ swz));
      bf16x8 kf1 = *reinterpret_cast<const bf16x8*>(kr + ((64 + lg * 16) ^ swz));
      s[c] = __builtin_amdgcn_mfma_f32_16x16x32_bf16(kf0, q0, z4, 0, 0, 0);
      s[c] = __builtin_amdgcn_mfma_f32_16x16x32_bf16(kf1, q1, s[c], 0, 0, 0);
    }
    __builtin_amdgcn_s_setprio(0);
    // ---- bias: wave-uniform fold for saturated tiles (84%), else per-elem
    float bu = 0.f;
    if (dkv >= 112) {
      bu = bias_hi;
    } else if (dkv <= -160) {
      bu = bias_lo;
    } else {
#pragma unroll
      for (int c = 0; c < 4; ++c)
#pragma unroll
        for (int r = 0; r < 4; ++r)
          s[c][r] += btab[dkv + c * 16 + lg * 4 + r - l15];
    }
    // ---- P = 2^(S - (FIXB - bu)), per-lane partial row sum
    const float mb = FIXB - bu;
#pragma unroll
    for (int c = 0; c < 4; ++c)
#pragma unroll
      for (int r = 0; r < 4; ++r) s[c][r] = __builtin_exp2f(s[c][r] - mb);
    float r0 = (s[0][0] + s[0][1]) + (s[0][2] + s[0][3]);
    float r1 = (s[1][0] + s[1][1]) + (s[1][2] + s[1][3]);
    float r2 = (s[2][0] + s[2][1]) + (s[2][2] + s[2][3]);
    float r3 = (s[3][0] + s[3][1]) + (s[3][2] + s[3][3]);
    l_r += (r0 + r1) + (r2 + r3);
    // ---- B-frags (P^T) in-register via hardware packed cvt (8 instr)
    int4 p0i, p1i;
    p0i.x = cvt_pk(s[0][0], s[0][1]); p0i.y = cvt_pk(s[0][2], s[0][3]);
    p0i.z = cvt_pk(s[1][0], s[1][1]); p0i.w = cvt_pk(s[1][2], s[1][3]);
    p1i.x = cvt_pk(s[2][0], s[2][1]); p1i.y = cvt_pk(s[2][2], s[2][3]);
    p1i.z = cvt_pk(s[3][0], s[3][1]); p1i.w = cvt_pk(s[3][2], s[3][3]);
    bf16x8 pb0 = *reinterpret_cast<bf16x8*>(&p0i);
    bf16x8 pb1 = *reinterpret_cast<bf16x8*>(&p1i);
    // ---- A-frags (V^T, permutation pre-baked in Vt): plain b128 reads
    const char* VsC = Vs[cur];
    __builtin_amdgcn_s_setprio(1);
#pragma unroll
    for (int d = 0; d < 4; ++d) {
      const char* vr = VsC + (d * 16 + l15) * 128;
      bf16x8 v0f = *reinterpret_cast<const bf16x8*>(vr + ((lg * 16) ^ swz));
      bf16x8 v1f = *reinterpret_cast<const bf16x8*>(vr + ((64 + lg * 16) ^ swz));
      o[d] = __builtin_amdgcn_mfma_f32_16x16x32_bf16(v0f, pb0, o[d], 0, 0, 0);
      o[d] = __builtin_amdgcn_mfma_f32_16x16x32_bf16(v1f, pb1, o[d], 0, 0, 0);
    }
    __builtin_amdgcn_s_setprio(0);
    // ---- counted wait: tile kt+1 ready; tile kt+2 stays in flight
    if (kt < 30) {
      asm volatile("s_waitcnt vmcnt(4)" ::: "memory");
    } else {
      asm volatile("s_waitcnt vmcnt(0)" ::: "memory");
    }
    __builtin_amdgcn_s_barrier();
    __builtin_amdgcn_sched_barrier(0);
    cur = cur + 1; if (cur >= 3) cur = 0;
  }
  // ---- epilogue: combine the 4 row-sharing lanes' partial l, then store
  l_r += __shfl_xor(l_r, 16, 64);
  l_r += __shfl_xor(l_r, 32, 64);
  float inv = 1.0f / l_r;
  const size_t orow = (size_t)(b * SEQ + qbase + l15) * HD + h * 64;
#pragma unroll
  for (int d = 0; d < 4; ++d) {
    int2 e;
    e.x = cvt_pk(o[d][0] * inv, o[d][1] * inv);
    e.y = cvt_pk(o[d][2] * inv, o[d][3] * inv);
    *reinterpret_cast<int2*>(&Ob[orow + d * 16 + lg * 4]) = e;
  }
}

// ---------------- launch ----------------
extern "C" void kernel_launch(void* const* d_in, const int* in_sizes, int n_in,
                              void* d_out, int out_size, void* d_ws, size_t ws_size,
                              hipStream_t stream) {
  const float* H    = (const float*)d_in[0];
  const float* Wq   = (const float*)d_in[1];
  const float* Wk   = (const float*)d_in[2];
  const float* Wv   = (const float*)d_in[3];
  const float* Wo   = (const float*)d_in[4];
  const float* relb = (const float*)d_in[5];

  char* ws = (char*)d_ws;
  short* Hb   = (short*)(ws);                        // 8 MB
  short* Wts  = (short*)(ws + ((size_t)8 << 20));    // 4 x 2 MB (WqT WkT WvT WoT)
  short* Qb   = (short*)(ws + ((size_t)16 << 20));   // 8 MB
  short* Kb   = (short*)(ws + ((size_t)24 << 20));   // 8 MB
  short* Vb   = (short*)(ws + ((size_t)32 << 20));   // 8 MB
  short* Vt   = (short*)(ws + ((size_t)40 << 20));   // 8 MB
  short* Ob   = (short*)(ws + ((size_t)48 << 20));   // 8 MB
  float* btab = (float*)(ws + ((size_t)56 << 20));   // 256 KB

  k_cvt_h<<<2048, 256, 0, stream>>>(H, Hb);
  k_wtrans<<<dim3(32, 32, 4), 256, 0, stream>>>(Wq, Wk, Wv, Wo, Wts);
  k_bias<<<256, 256, 0, stream>>>(relb, btab);

  // QKV fused over z: C = Hb * W{q,k,v}^T  (writes Qb, Kb, Vb via cz stride)
  k_gemm_bt<0><<<dim3(8, 32, 3), 256, 0, stream>>>(
      Hb, Wts, Qb, (size_t)1024 * 1024, (size_t)4096 * 1024);

  k_vtrans<<<dim3(32, 32), 256, 0, stream>>>(Vb, Vt);
  k_attn<<<1024, 256, 0, stream>>>(Qb, Kb, Vt, btab, Ob);

  // out = Ob * Wo^T
  k_gemm_bt<1><<<dim3(8, 32, 1), 256, 0, stream>>>(
      Ob, Wts + (size_t)3 * 1024 * 1024, d_out, 0, 0);
}

// Round 13
// 205.725 us; speedup vs baseline: 1.1041x; 1.1041x over previous
//
#include <hip/hip_runtime.h>
#include <hip/hip_bf16.h>
#include <math.h>

#define DM   1024
#define HD   1024
#define NH   16
#define DK   64
#define SEQ  2048
#define BATCH 2

#define LOG2E 1.4426950408889634f
#define FIXB 32.0f   // fixed softmax base (log2 domain); |logits| << 32+120

typedef __attribute__((ext_vector_type(8))) short bf16x8;
typedef __attribute__((ext_vector_type(4))) float f32x4;

static __device__ __forceinline__ short f2b(float f) {
  union { float f; unsigned u; } v; v.f = f;
  unsigned r = (v.u + 0x7fffu + ((v.u >> 16) & 1u)) >> 16;
  return (short)r;
}

// HW packed f32->bf16 (RNE), lo = src0, hi = src1  [T12, gfx950]
static __device__ __forceinline__ int cvt_pk(float lo, float hi) {
  int r;
  asm("v_cvt_pk_bf16_f32 %0, %1, %2" : "=v"(r) : "v"(lo), "v"(hi));
  return r;
}

static __device__ __forceinline__ void gload_lds16(const void* g, void* l) {
  __builtin_amdgcn_global_load_lds(
      (const __attribute__((address_space(1))) void*)g,
      (__attribute__((address_space(3))) void*)l, 16, 0, 0);
}

// ---------------- prep kernels ----------------

__global__ __launch_bounds__(256) void k_cvt_h(const float* __restrict__ in,
                                               short* __restrict__ out) {
  int i = (blockIdx.x * 256 + threadIdx.x) * 8;
  float4 a = *reinterpret_cast<const float4*>(in + i);
  float4 b = *reinterpret_cast<const float4*>(in + i + 4);
  bf16x8 o;
  o[0] = f2b(a.x); o[1] = f2b(a.y); o[2] = f2b(a.z); o[3] = f2b(a.w);
  o[4] = f2b(b.x); o[5] = f2b(b.y); o[6] = f2b(b.z); o[7] = f2b(b.w);
  *reinterpret_cast<bf16x8*>(out + i) = o;
}

// transpose + convert 1024x1024 fp32 [K][N] -> bf16 [N][K]; z selects matrix.
// Wq (z==0) is pre-scaled by log2e so attention logits are in log2 domain.
__global__ __launch_bounds__(256) void k_wtrans(const float* __restrict__ Wq,
                                                const float* __restrict__ Wk,
                                                const float* __restrict__ Wv,
                                                const float* __restrict__ Wo,
                                                short* __restrict__ Wts) {
  const float* src = (blockIdx.z == 0) ? Wq : (blockIdx.z == 1) ? Wk
                   : (blockIdx.z == 2) ? Wv : Wo;
  const float scl = (blockIdx.z == 0) ? LOG2E : 1.0f;
  short* dst = Wts + (size_t)blockIdx.z * DM * HD;
  __shared__ float t[32][33];
  int tx = threadIdx.x & 31, ty = threadIdx.x >> 5;  // ty 0..7
  int k0 = blockIdx.y * 32, n0 = blockIdx.x * 32;
#pragma unroll
  for (int i = 0; i < 4; ++i)
    t[ty + i * 8][tx] = src[(size_t)(k0 + ty + i * 8) * 1024 + n0 + tx];
  __syncthreads();
#pragma unroll
  for (int i = 0; i < 4; ++i)
    dst[(size_t)(n0 + ty + i * 8) * 1024 + k0 + tx] = f2b(t[tx][ty + i * 8] * scl);
}

// bias table (scaled by log2e): btab[h][pos], pos = delta + 2047, delta = kv-q
__global__ __launch_bounds__(256) void k_bias(const float* __restrict__ rel_bias,
                                              float* __restrict__ btab) {
  int idx = blockIdx.x * 256 + threadIdx.x;  // 65536
  int h = idx >> 12, pos = idx & 4095;
  int delta = pos - 2047;
  int rb = (delta > 0) ? 16 : 0;
  int ar = (delta < 0) ? -delta : delta;
  int bb;
  if (ar < 8) bb = ar;
  else {
    bb = 8 + (int)(logf((float)ar * 0.125f) * (8.0f / 2.7725887222397811f));
    if (bb > 15) bb = 15;
  }
  btab[idx] = rel_bias[(rb + bb) * NH + h] * LOG2E;
}

// V [4096][1024] bf16 -> Vt[bh][dk=64][seq=2048] with the PV k-permutation
// baked in: within each 32-kv chunk, 4-kv blocks stored in order
// [0,4,1,5,2,6,3,7] so lane lg's PV A-frag (kv lg*4+r and 16+lg*4+r) is one
// contiguous b128 at byte offset lg*16 / 64+lg*16.
__global__ __launch_bounds__(256) void k_vtrans(const short* __restrict__ Vb,
                                                short* __restrict__ Vt) {
  int bh = blockIdx.y, b = bh >> 4, h = bh & 15;
  int st = blockIdx.x * 64;
  __shared__ short t[64][72];
  int tx = threadIdx.x & 15, ty = threadIdx.x >> 4;
#pragma unroll
  for (int i = 0; i < 4; ++i) {
    int row = ty + i * 16;
    *reinterpret_cast<short4*>(&t[row][tx * 4]) =
        *reinterpret_cast<const short4*>(
            &Vb[(size_t)(b * SEQ + st + row) * HD + h * 64 + tx * 4]);
  }
  __syncthreads();
  const int chunk = tx >> 3, bb = tx & 7;
  const int p = ((bb & 3) << 1) | (bb >> 2);  // stored block position
  const int kvpos = st + chunk * 32 + p * 4;
#pragma unroll
  for (int i = 0; i < 4; ++i) {
    int dk = ty + i * 16;
    short4 v = make_short4(t[tx * 4 + 0][dk], t[tx * 4 + 1][dk],
                           t[tx * 4 + 2][dk], t[tx * 4 + 3][dk]);
    *reinterpret_cast<short4*>(
        &Vt[(size_t)bh * DK * SEQ + (size_t)dk * SEQ + kvpos]) = v;
  }
}

// ---------------- GEMM: C[M][N=1024] = A[M][1024]bf16 * Bt[1024][1024]^T ----
// 128xTN tile, 4 waves (2x2), K-step 32, 2-phase double-buffered.
// TN=128: wave covers 64x64 (QKV). TN=64: wave covers 64x32, grid doubles ->
// 2 blocks/CU for the out-proj (TLP for latency hiding).
template <int OUTF32, int TN>
__global__ __launch_bounds__(256) void k_gemm_bt(const short* __restrict__ A,
                                                 const short* __restrict__ Bt,
                                                 void* __restrict__ Cv,
                                                 size_t btz, size_t cz) {
  constexpr int NN = TN / 32;   // B-frags per wave
  constexpr int CW = TN / 2;    // cols per wave
  __shared__ __align__(16) short As[2][128 * 32];
  __shared__ __align__(16) short Bs[2][TN * 32];
  const int tid = threadIdx.x, w = tid >> 6, lane = tid & 63;
  const int wr = w >> 1, wc = w & 1, lg = lane >> 4, l15 = lane & 15;
  const int rowBase = blockIdx.y * 128, colBase = blockIdx.x * TN;
  const short* B = Bt + (size_t)blockIdx.z * btz;

  f32x4 acc[4][NN];
#pragma unroll
  for (int m = 0; m < 4; ++m)
#pragma unroll
    for (int n = 0; n < NN; ++n) acc[m][n] = (f32x4){0.f, 0.f, 0.f, 0.f};

  const int c1 = w * 64 + lane, c2 = c1 + 256;
  const short* Ap1 = A + (size_t)(rowBase + (c1 >> 2)) * 1024 + (c1 & 3) * 8;
  const short* Ap2 = A + (size_t)(rowBase + (c2 >> 2)) * 1024 + (c2 & 3) * 8;
  const short* Bp1 = B + (size_t)(colBase + (c1 >> 2)) * 1024 + (c1 & 3) * 8;
  const short* Bp2 = B + (size_t)(colBase + (c2 >> 2)) * 1024 + (c2 & 3) * 8;

  // prologue: stage K-tile 0 into buffer 0
  {
    char* AsB = (char*)As[0];
    char* BsB = (char*)Bs[0];
    gload_lds16(Ap1, AsB + w * 1024);
    gload_lds16(Ap2, AsB + 4096 + w * 1024);
    gload_lds16(Bp1, BsB + w * 1024);
    if (TN == 128) gload_lds16(Bp2, BsB + 4096 + w * 1024);
  }
  asm volatile("s_waitcnt vmcnt(0)" ::: "memory");
  __syncthreads();

#pragma unroll 2
  for (int k0 = 0; k0 < 1024; k0 += 32) {
    const int cu = (k0 >> 5) & 1;
    // issue next K-tile into the other buffer (overlaps with compute)
    if (k0 + 32 < 1024) {
      char* AsB = (char*)As[cu ^ 1];
      char* BsB = (char*)Bs[cu ^ 1];
      gload_lds16(Ap1 + k0 + 32, AsB + w * 1024);
      gload_lds16(Ap2 + k0 + 32, AsB + 4096 + w * 1024);
      gload_lds16(Bp1 + k0 + 32, BsB + w * 1024);
      if (TN == 128) gload_lds16(Bp2 + k0 + 32, BsB + 4096 + w * 1024);
    }
    bf16x8 af[4], bfr[NN];
#pragma unroll
    for (int m = 0; m < 4; ++m)
      af[m] = *reinterpret_cast<const bf16x8*>(
          &As[cu][(wr * 64 + m * 16 + l15) * 32 + lg * 8]);
#pragma unroll
    for (int n = 0; n < NN; ++n)
      bfr[n] = *reinterpret_cast<const bf16x8*>(
          &Bs[cu][(wc * CW + n * 16 + l15) * 32 + lg * 8]);
#pragma unroll
    for (int m = 0; m < 4; ++m)
#pragma unroll
      for (int n = 0; n < NN; ++n)
        acc[m][n] =
            __builtin_amdgcn_mfma_f32_16x16x32_bf16(af[m], bfr[n], acc[m][n], 0, 0, 0);
    // staged loads landed; all waves done reading [cu]
    asm volatile("s_waitcnt vmcnt(0)" ::: "memory");
    __syncthreads();
  }

#pragma unroll
  for (int m = 0; m < 4; ++m)
#pragma unroll
    for (int n = 0; n < NN; ++n) {
      int col = colBase + wc * CW + n * 16 + l15;
#pragma unroll
      for (int r = 0; r < 4; ++r) {
        int row = rowBase + wr * 64 + m * 16 + lg * 4 + r;
        if (OUTF32)
          ((float*)Cv)[(size_t)row * 1024 + col] = acc[m][n][r];
        else
          ((short*)Cv + (size_t)blockIdx.z * cz)[(size_t)row * 1024 + col] =
              f2b(acc[m][n][r]);
      }
    }
}

// ---------------- flash attention (fixed-base softmax, zero-shuffle PV) -----
// 8 waves/block (512 thr), QBLK=128: K/V tile shared by 8 waves -> staging
// loads/wave and per-(b,h) L2 traffic halve vs 4-wave blocks.
// K/V tiles: LDS(row, cb) = G(row, cb ^ ((row&7)<<4)) — linear gload_lds dest,
// inverse-swizzled per-lane global source, swizzled ds_read (rule 21 / T2).
static __device__ __forceinline__ void stage_tile8(const char* gbase, size_t grs,
                                                   char* lbase, int tid) {
  const int r0 = tid >> 3;            // 0..63
  const int cb = (tid & 7) * 16;
  const int sw = (r0 & 7) << 4;
  gload_lds16(gbase + (size_t)r0 * grs + (cb ^ sw), lbase + (tid & ~63) * 16);
}

// Fixed-base softmax: P = 2^(S - 32), l = sum P, out = (sum P*V)/l.
__global__ __launch_bounds__(512, 4) void k_attn(const short* __restrict__ Qb,
                                                 const short* __restrict__ Kb,
                                                 const short* __restrict__ Vt,
                                                 const float* __restrict__ biasTab,
                                                 short* __restrict__ Ob) {
  const int j = blockIdx.x;
  const int orig = (j & 7) * 64 + (j >> 3);  // bijective XCD swizzle (512%8==0)
  const int qt = orig & 15, bh = orig >> 4;
  const int b = bh >> 4, h = bh & 15;
  const int tid = threadIdx.x;
  const int w = tid >> 6, lane = tid & 63;
  const int lg = lane >> 4, l15 = lane & 15;
  const int qbase = qt * 128 + w * 16;

  __shared__ __align__(16) char Ks[2][8192];
  __shared__ __align__(16) char Vs[2][8192];
  const int swz = (l15 & 7) << 4;

  const short* Qrow = Qb + (size_t)(b * SEQ + qbase + l15) * HD + h * 64 + lg * 8;
  bf16x8 q0 = *reinterpret_cast<const bf16x8*>(Qrow);
  bf16x8 q1 = *reinterpret_cast<const bf16x8*>(Qrow + 32);

  const char* Kg = (const char*)(Kb + (size_t)(b * SEQ) * HD + h * 64);
  const char* Vg = (const char*)(Vt + (size_t)bh * DK * SEQ);
  const float* btab = biasTab + h * 4096 + 2047;
  const float bias_hi = btab[1024];   // saturated delta >= +91
  const float bias_lo = btab[-1024];  // saturated delta <= -91

  f32x4 o[4];
#pragma unroll
  for (int c = 0; c < 4; ++c) o[c] = (f32x4){0.f, 0.f, 0.f, 0.f};
  float l_r = 0.f;

  const f32x4 z4 = (f32x4){0.f, 0.f, 0.f, 0.f};

  // prologue: stage tile 0
  stage_tile8(Kg, 2048, Ks[0], tid);
  stage_tile8(Vg, 4096, Vs[0], tid);
  asm volatile("s_waitcnt vmcnt(0)" ::: "memory");
  __syncthreads();

#pragma unroll 2
  for (int kt = 0; kt < 32; ++kt) {
    const int cu = kt & 1;
    const int kvb = kt * 64;
    const int dkv = kvb - qbase;
    // ---- issue next-tile staging (overlaps with this tile's compute)
    if (kt < 31) {
      stage_tile8(Kg + (size_t)(kvb + 64) * 2048, 2048, Ks[cu ^ 1], tid);
      stage_tile8(Vg + (size_t)(kvb + 64) * 2, 4096, Vs[cu ^ 1], tid);
    }
    // ---- S^T = K Q^T : col=q(l15), row=kv(c*16+lg*4+r); log2 domain
    const char* KsC = Ks[cu];
    f32x4 s[4];
    __builtin_amdgcn_s_setprio(1);
#pragma unroll
    for (int c = 0; c < 4; ++c) {
      const char* kr = KsC + (c * 16 + l15) * 128;
      bf16x8 kf0 = *reinterpret_cast<const bf16x8*>(kr + ((lg * 16) ^ swz));
      bf16x8 kf1 = *reinterpret_cast<const bf16x8*>(kr + ((64 + lg * 16) ^ swz));
      s[c] = __builtin_amdgcn_mfma_f32_16x16x32_bf16(kf0, q0, z4, 0, 0, 0);
      s[c] = __builtin_amdgcn_mfma_f32_16x16x32_bf16(kf1, q1, s[c], 0, 0, 0);
    }
    __builtin_amdgcn_s_setprio(0);
    // ---- bias: wave-uniform fold for saturated tiles, else per-elem
    float bu = 0.f;
    if (dkv >= 112) {
      bu = bias_hi;
    } else if (dkv <= -160) {
      bu = bias_lo;
    } else {
#pragma unroll
      for (int c = 0; c < 4; ++c)
#pragma unroll
        for (int r = 0; r < 4; ++r)
          s[c][r] += btab[dkv + c * 16 + lg * 4 + r - l15];
    }
    // ---- P = 2^(S - (FIXB - bu)), per-lane partial row sum
    const float mb = FIXB - bu;
#pragma unroll
    for (int c = 0; c < 4; ++c)
#pragma unroll
      for (int r = 0; r < 4; ++r) s[c][r] = __builtin_exp2f(s[c][r] - mb);
    float r0 = (s[0][0] + s[0][1]) + (s[0][2] + s[0][3]);
    float r1 = (s[1][0] + s[1][1]) + (s[1][2] + s[1][3]);
    float r2 = (s[2][0] + s[2][1]) + (s[2][2] + s[2][3]);
    float r3 = (s[3][0] + s[3][1]) + (s[3][2] + s[3][3]);
    l_r += (r0 + r1) + (r2 + r3);
    // ---- B-frags (P^T) in-register via hardware packed cvt (8 instr)
    int4 p0i, p1i;
    p0i.x = cvt_pk(s[0][0], s[0][1]); p0i.y = cvt_pk(s[0][2], s[0][3]);
    p0i.z = cvt_pk(s[1][0], s[1][1]); p0i.w = cvt_pk(s[1][2], s[1][3]);
    p1i.x = cvt_pk(s[2][0], s[2][1]); p1i.y = cvt_pk(s[2][2], s[2][3]);
    p1i.z = cvt_pk(s[3][0], s[3][1]); p1i.w = cvt_pk(s[3][2], s[3][3]);
    bf16x8 pb0 = *reinterpret_cast<bf16x8*>(&p0i);
    bf16x8 pb1 = *reinterpret_cast<bf16x8*>(&p1i);
    // ---- A-frags (V^T, permutation pre-baked in Vt): plain b128 reads
    const char* VsC = Vs[cu];
    __builtin_amdgcn_s_setprio(1);
#pragma unroll
    for (int d = 0; d < 4; ++d) {
      const char* vr = VsC + (d * 16 + l15) * 128;
      bf16x8 v0f = *reinterpret_cast<const bf16x8*>(vr + ((lg * 16) ^ swz));
      bf16x8 v1f = *reinterpret_cast<const bf16x8*>(vr + ((64 + lg * 16) ^ swz));
      o[d] = __builtin_amdgcn_mfma_f32_16x16x32_bf16(v0f, pb0, o[d], 0, 0, 0);
      o[d] = __builtin_amdgcn_mfma_f32_16x16x32_bf16(v1f, pb1, o[d], 0, 0, 0);
    }
    __builtin_amdgcn_s_setprio(0);
    // ---- staged loads landed; all waves done with [cu]
    asm volatile("s_waitcnt vmcnt(0)" ::: "memory");
    __syncthreads();
  }
  // ---- epilogue: combine the 4 row-sharing lanes' partial l, then store
  l_r += __shfl_xor(l_r, 16, 64);
  l_r += __shfl_xor(l_r, 32, 64);
  float inv = 1.0f / l_r;
  const size_t orow = (size_t)(b * SEQ + qbase + l15) * HD + h * 64;
#pragma unroll
  for (int d = 0; d < 4; ++d) {
    int2 e;
    e.x = cvt_pk(o[d][0] * inv, o[d][1] * inv);
    e.y = cvt_pk(o[d][2] * inv, o[d][3] * inv);
    *reinterpret_cast<int2*>(&Ob[orow + d * 16 + lg * 4]) = e;
  }
}

// ---------------- launch ----------------
extern "C" void kernel_launch(void* const* d_in, const int* in_sizes, int n_in,
                              void* d_out, int out_size, void* d_ws, size_t ws_size,
                              hipStream_t stream) {
  const float* H    = (const float*)d_in[0];
  const float* Wq   = (const float*)d_in[1];
  const float* Wk   = (const float*)d_in[2];
  const float* Wv   = (const float*)d_in[3];
  const float* Wo   = (const float*)d_in[4];
  const float* relb = (const float*)d_in[5];

  char* ws = (char*)d_ws;
  short* Hb   = (short*)(ws);                        // 8 MB
  short* Wts  = (short*)(ws + ((size_t)8 << 20));    // 4 x 2 MB (WqT WkT WvT WoT)
  short* Qb   = (short*)(ws + ((size_t)16 << 20));   // 8 MB
  short* Kb   = (short*)(ws + ((size_t)24 << 20));   // 8 MB
  short* Vb   = (short*)(ws + ((size_t)32 << 20));   // 8 MB
  short* Vt   = (short*)(ws + ((size_t)40 << 20));   // 8 MB
  short* Ob   = (short*)(ws + ((size_t)48 << 20));   // 8 MB
  float* btab = (float*)(ws + ((size_t)56 << 20));   // 256 KB

  k_cvt_h<<<2048, 256, 0, stream>>>(H, Hb);
  k_wtrans<<<dim3(32, 32, 4), 256, 0, stream>>>(Wq, Wk, Wv, Wo, Wts);
  k_bias<<<256, 256, 0, stream>>>(relb, btab);

  // QKV fused over z: C = Hb * W{q,k,v}^T  (writes Qb, Kb, Vb via cz stride)
  k_gemm_bt<0, 128><<<dim3(8, 32, 3), 256, 0, stream>>>(
      Hb, Wts, Qb, (size_t)1024 * 1024, (size_t)4096 * 1024);

  k_vtrans<<<dim3(32, 32), 256, 0, stream>>>(Vb, Vt);
  k_attn<<<512, 512, 0, stream>>>(Qb, Kb, Vt, btab, Ob);

  // out = Ob * Wo^T  (64-col tiles -> 512 blocks = 2/CU)
  k_gemm_bt<1, 64><<<dim3(16, 32, 1), 256, 0, stream>>>(
      Ob, Wts + (size_t)3 * 1024 * 1024, d_out, 0, 0);
}